// Round 2
// 85.897 us; speedup vs baseline: 1.0173x; 1.0173x over previous
//
#include <hip/hip_runtime.h>

// OPU via MFMA. R17 = R15 two-kernel structure + (a) W-presplit folded into the 512
// X-blocks (one balanced residency pass, was 768 blocks = 1.5 passes @2/CU) + (b)
// biased-magic quant in main (res held at 1.5*2^23 so fp32 RNE in `res += acc` IS the
// per-chunk ADC rint; saves 1024 v_rndne/wave, quant VALU was > MFMA pipe time/SIMD).
// R16 post-mortem: hipLaunchCooperativeKernel never executed (absmax 3824 == max|ref|
// => output all-zero, launch error unchecked). Coop launch is banned; fusion, if
// retried, will be a hand-rolled resident-grid barrier under a normal launch.
// Biased-quant safety: |res - RBIAS| <= 16 chunks * 70 = 1120 << 4.19M margin, ulp=1.0
// throughout; ties need ~17 random fraction bits to vanish (~2^-17/chunk) -> worst-case
// rare +-16 flips; threshold 76.48 allows 4 grid steps, R15 absmax was 16.
// Carried: merged-plane layout (4KB page/chunk), table-driven presplit (bit-identical),
// literal double-buffer, round-interleaved 12 MFMA/chunk (AlBl dropped, |err|<=4e-6),
// clip provably dead (|mm/16|<=68.9<127.5), 4-barrier LDS combine, x16 store,
// per-XCD A 2MB + B 2MB swizzle.

typedef unsigned int u32;
typedef unsigned short u16;
typedef _Float16 f16x8 __attribute__((ext_vector_type(8)));
typedef float f32x16 __attribute__((ext_vector_type(16)));

#define M_TOT 2048
#define N_TOT 1024
#define K_TOT 1024
#define RBIAS 12582912.0f  // 1.5 * 2^23: fp32 ulp = 1.0, integer-grid RNE in the add

__device__ __forceinline__ u32 split_pack(float a) {
  _Float16 h = (_Float16)a;              // v_cvt_f16_f32 (RNE)
  _Float16 l = (_Float16)(a - (float)h); // exact fp32 sub then RNE
  return (u32)__builtin_bit_cast(u16, h) | ((u32)__builtin_bit_cast(u16, l) << 16);
}
__device__ __forceinline__ u32 pk_lo(u32 a, u32 b) { return (a & 0xffffu) | (b << 16); }
__device__ __forceinline__ u32 pk_hi(u32 a, u32 b) { return (a >> 16) | (b & 0xffff0000u); }

__global__ __launch_bounds__(256) void presplit(
    const float* __restrict__ x, const float* __restrict__ w,
    const float* __restrict__ vl, const float* __restrict__ wl,
    u16* __restrict__ XHL, u16* __restrict__ WHL)
{
  __shared__ __align__(16) char lds[16384];  // X 4-chunk plane image
  __shared__ u32 tabX[256];
  __shared__ u32 tabW[256];

  const int b   = blockIdx.x;   // 512 blocks: each does one X tile-group AND one W slice
  const int tid = threadIdx.x;

  // ---- split tables: a = fl(x + vlut) (X) and fl(fl(w + wlut) * 1/16) (W) ----
  {
    const int j = tid >> 4, xi = tid & 15;
    const float base = (float)(xi - 8);
    tabX[tid] = split_pack(base + vl[j * 16 + xi]);
    tabW[tid] = split_pack((base + wl[j * 16 + xi]) * 0.0625f);
  }
  __syncthreads();

  // ---- W presplit: thread = one (ch, oct, n) item; 512*256 == 128*1024 exactly ----
  {
    const int g2 = b * 256 + tid;
    const int n  = g2 & 1023;
    const int co = g2 >> 10;                // 0..127 = (ch, oct)
    const int ch = co >> 1, oct = co & 1;
    const int nblk = n >> 6, ng = (n >> 5) & 1, n32 = n & 31;
    const float* wp = w + (size_t)(ch * 16 + oct * 8) * N_TOT + n;

    u32 hp[4], lp[4];
#pragma unroll
    for (int e2 = 0; e2 < 4; ++e2) {
      const int e = e2 * 2;
      const float w0 = wp[(size_t)e * N_TOT];
      const float w1 = wp[(size_t)(e + 1) * N_TOT];
      const u32 t0 = tabW[(oct * 8 + e) * 16 + (int)(w0 + 8.0f)];
      const u32 t1 = tabW[(oct * 8 + e + 1) * 16 + (int)(w1 + 8.0f)];
      hp[e2] = pk_lo(t0, t1);
      lp[e2] = pk_hi(t0, t1);
    }
    // chunk base (u16): (nblk*64+ch)*2048 ; layout hl*1024 + ng*512 + oct*256 + n32*8
    const size_t wb = (size_t)(nblk * 64 + ch) * 2048 + ng * 512 + oct * 256 + n32 * 8;
    *(uint4*)&WHL[wb]        = make_uint4(hp[0], hp[1], hp[2], hp[3]);
    *(uint4*)&WHL[wb + 1024] = make_uint4(lp[0], lp[1], lp[2], lp[3]);
  }

  // ---- X presplit: block = (mblk, chunk-group of 4); identical to R15 ----
  {
    const int mblk = b >> 4, chg = b & 15;
    const int ml = tid >> 2, chl = tid & 3;
    const int rg = ml >> 5, row = ml & 31;
    const float4* xp4 = (const float4*)(x + (size_t)(mblk * 64 + ml) * K_TOT + (chg * 4 + chl) * 16);
    float4 v4[4] = { xp4[0], xp4[1], xp4[2], xp4[3] };
    const float* v = (const float*)v4;

    u32 hp[8], lp[8];
#pragma unroll
    for (int e2 = 0; e2 < 8; ++e2) {
      const int e = e2 * 2;
      const u32 t0 = tabX[e * 16 + (int)(v[e] + 8.0f)];
      const u32 t1 = tabX[(e + 1) * 16 + (int)(v[e + 1] + 8.0f)];
      hp[e2] = pk_lo(t0, t1);
      lp[e2] = pk_hi(t0, t1);
    }

    // LDS image in exact global layout: chl*4096 + hl*2048 + rg*1024 + oct*512 + row*16
    char* basep = lds + chl * 4096 + rg * 1024 + row * 16;
    *(uint4*)(basep)        = make_uint4(hp[0], hp[1], hp[2], hp[3]);  // h oct0
    *(uint4*)(basep + 512)  = make_uint4(hp[4], hp[5], hp[6], hp[7]);  // h oct1
    *(uint4*)(basep + 2048) = make_uint4(lp[0], lp[1], lp[2], lp[3]);  // l oct0
    *(uint4*)(basep + 2560) = make_uint4(lp[4], lp[5], lp[6], lp[7]);  // l oct1
    __syncthreads();

    // coalesced dump: 16KB contiguous (4 chunk-planes)
    const size_t gb = (size_t)(mblk * 64 + chg * 4) * 4096;  // bytes
    const int off = tid * 16;
    *(uint4*)((char*)XHL + gb + off)         = *(const uint4*)(lds + off);
    *(uint4*)((char*)XHL + gb + off + 4096)  = *(const uint4*)(lds + off + 4096);
    *(uint4*)((char*)XHL + gb + off + 8192)  = *(const uint4*)(lds + off + 8192);
    *(uint4*)((char*)XHL + gb + off + 12288) = *(const uint4*)(lds + off + 12288);
  }
}

__global__ __launch_bounds__(256, 2) void opu_main(
    const u16* __restrict__ XHL, const u16* __restrict__ WHL,
    float* __restrict__ out)
{
  __shared__ float cb[64 * 64];   // 16KB combine buffer

  const int tid  = threadIdx.x;
  const int wave = tid >> 6;      // k-slice: chunks [wave*16, wave*16+16)
  const int lane = tid & 63;
  const int oct  = lane >> 5;
  const int ll   = lane & 31;

  const int bx   = blockIdx.x;
  const int nblk = (bx & 1) + 2 * ((bx >> 3) & 7);   // 0..15
  const int mblk = ((bx >> 1) & 3) + 4 * (bx >> 6);  // 0..31

  // chunk stride 2048 u16 (4KB page: [hl][rg|ng][oct][32][k8])
  const u16* pA = XHL + (size_t)mblk * 131072 + (size_t)(wave * 16) * 2048 + lane * 8;
  const u16* pB = WHL + (size_t)nblk * 131072 + (size_t)(wave * 16) * 2048 + lane * 8;

  uint4 b0[8], b1[8];  // literal-indexed only (R7 lesson: %3 ring -> scratch spill)

#define LOADCH(dst, off)                                  \
  do {                                                    \
    (dst)[0] = *(const uint4*)(pA + (off));               \
    (dst)[1] = *(const uint4*)(pA + (off) + 512);         \
    (dst)[2] = *(const uint4*)(pA + (off) + 1024);        \
    (dst)[3] = *(const uint4*)(pA + (off) + 1536);        \
    (dst)[4] = *(const uint4*)(pB + (off));               \
    (dst)[5] = *(const uint4*)(pB + (off) + 512);         \
    (dst)[6] = *(const uint4*)(pB + (off) + 1024);        \
    (dst)[7] = *(const uint4*)(pB + (off) + 1536);        \
  } while (0)

  float res[4][16];
#pragma unroll
  for (int t = 0; t < 4; ++t)
#pragma unroll
    for (int i = 0; i < 16; ++i) res[t][i] = RBIAS;   // biased: each add RNE-rounds to int grid
  const f32x16 fzero = {};

  // Round-interleaved: 4 live accs; biased res += acc performs the per-chunk ADC rint.
#define COMPUTE(c)                                                                     \
  do {                                                                                 \
    const f16x8 Ah0 = __builtin_bit_cast(f16x8, (c)[0]);                               \
    const f16x8 Ah1 = __builtin_bit_cast(f16x8, (c)[1]);                               \
    const f16x8 Al0 = __builtin_bit_cast(f16x8, (c)[2]);                               \
    const f16x8 Al1 = __builtin_bit_cast(f16x8, (c)[3]);                               \
    const f16x8 Bh0 = __builtin_bit_cast(f16x8, (c)[4]);                               \
    const f16x8 Bh1 = __builtin_bit_cast(f16x8, (c)[5]);                               \
    const f16x8 Bl0 = __builtin_bit_cast(f16x8, (c)[6]);                               \
    const f16x8 Bl1 = __builtin_bit_cast(f16x8, (c)[7]);                               \
    f32x16 a0 = __builtin_amdgcn_mfma_f32_32x32x16_f16(Ah0, Bh0, fzero, 0, 0, 0);      \
    f32x16 a1 = __builtin_amdgcn_mfma_f32_32x32x16_f16(Ah0, Bh1, fzero, 0, 0, 0);      \
    f32x16 a2 = __builtin_amdgcn_mfma_f32_32x32x16_f16(Ah1, Bh0, fzero, 0, 0, 0);      \
    f32x16 a3 = __builtin_amdgcn_mfma_f32_32x32x16_f16(Ah1, Bh1, fzero, 0, 0, 0);      \
    a0 = __builtin_amdgcn_mfma_f32_32x32x16_f16(Al0, Bh0, a0, 0, 0, 0);                \
    a1 = __builtin_amdgcn_mfma_f32_32x32x16_f16(Al0, Bh1, a1, 0, 0, 0);                \
    a2 = __builtin_amdgcn_mfma_f32_32x32x16_f16(Al1, Bh0, a2, 0, 0, 0);                \
    a3 = __builtin_amdgcn_mfma_f32_32x32x16_f16(Al1, Bh1, a3, 0, 0, 0);                \
    a0 = __builtin_amdgcn_mfma_f32_32x32x16_f16(Ah0, Bl0, a0, 0, 0, 0);                \
    a1 = __builtin_amdgcn_mfma_f32_32x32x16_f16(Ah0, Bl1, a1, 0, 0, 0);                \
    a2 = __builtin_amdgcn_mfma_f32_32x32x16_f16(Ah1, Bl0, a2, 0, 0, 0);                \
    a3 = __builtin_amdgcn_mfma_f32_32x32x16_f16(Ah1, Bl1, a3, 0, 0, 0);                \
    _Pragma("unroll")                                                                  \
    for (int i = 0; i < 16; ++i) res[0][i] += a0[i];                                   \
    _Pragma("unroll")                                                                  \
    for (int i = 0; i < 16; ++i) res[1][i] += a1[i];                                   \
    _Pragma("unroll")                                                                  \
    for (int i = 0; i < 16; ++i) res[2][i] += a2[i];                                   \
    _Pragma("unroll")                                                                  \
    for (int i = 0; i < 16; ++i) res[3][i] += a3[i];                                   \
  } while (0)

  LOADCH(b0, 0);
#pragma unroll 1
  for (int c2 = 0; c2 < 8; ++c2) {
    const size_t o = (size_t)c2 * 4096;          // 2 chunks of 2048 u16
    LOADCH(b1, o + 2048);                        // prefetch odd chunk
    COMPUTE(b0);
    if (c2 < 7) LOADCH(b0, o + 4096);            // prefetch next even chunk
    COMPUTE(b1);
  }

  // ---- combine the 4 waves' k-slices through LDS (subtract bias -> exact ints) ----
#define CBIDX(mt, nt, i) ((((mt) * 32) + ((i & 3) + 8 * (i >> 2) + 4 * oct)) * 64 + (nt) * 32 + ll)
  if (wave == 0) {
#pragma unroll
    for (int mt = 0; mt < 2; ++mt)
#pragma unroll
      for (int nt = 0; nt < 2; ++nt)
#pragma unroll
        for (int i = 0; i < 16; ++i) cb[CBIDX(mt, nt, i)] = res[mt * 2 + nt][i] - RBIAS;
  }
  __syncthreads();
  if (wave == 1) {
#pragma unroll
    for (int mt = 0; mt < 2; ++mt)
#pragma unroll
      for (int nt = 0; nt < 2; ++nt)
#pragma unroll
        for (int i = 0; i < 16; ++i) cb[CBIDX(mt, nt, i)] += res[mt * 2 + nt][i] - RBIAS;
  }
  __syncthreads();
  if (wave == 2) {
#pragma unroll
    for (int mt = 0; mt < 2; ++mt)
#pragma unroll
      for (int nt = 0; nt < 2; ++nt)
#pragma unroll
        for (int i = 0; i < 16; ++i) cb[CBIDX(mt, nt, i)] += res[mt * 2 + nt][i] - RBIAS;
  }
  __syncthreads();
  if (wave == 3) {
#pragma unroll
    for (int mt = 0; mt < 2; ++mt)
#pragma unroll
      for (int nt = 0; nt < 2; ++nt)
#pragma unroll
        for (int i = 0; i < 16; ++i) cb[CBIDX(mt, nt, i)] += res[mt * 2 + nt][i] - RBIAS;
  }
  __syncthreads();

  // ---- cooperative x16 store ----
  const float4* cbv = (const float4*)cb;
  const int row = tid >> 2, c4 = tid & 3;
  float* orow = out + (size_t)(mblk * 64 + row) * N_TOT + nblk * 64;
#pragma unroll
  for (int p = 0; p < 4; ++p) {
    float4 vv = cbv[row * 16 + c4 + 4 * p];
    vv.x *= 16.0f; vv.y *= 16.0f; vv.z *= 16.0f; vv.w *= 16.0f;
    *(float4*)&orow[(c4 + 4 * p) * 4] = vv;
  }
}

extern "C" void kernel_launch(void* const* d_in, const int* in_sizes, int n_in,
                              void* d_out, int out_size, void* d_ws, size_t ws_size,
                              hipStream_t stream)
{
  const float* input  = (const float*)d_in[0];
  const float* weight = (const float*)d_in[1];
  const float* vmap   = (const float*)d_in[2];
  const float* wmap   = (const float*)d_in[3];
  float* out = (float*)d_out;

  u16* XHL = (u16*)d_ws;                         // 8MB (4M u16)
  u16* WHL = XHL + 4 * 1024 * 1024;              // 4MB   (ws use: 12MB total)

  presplit<<<512, 256, 0, stream>>>(input, weight, vmap, wmap, XHL, WHL);

  opu_main<<<512, 256, 0, stream>>>(XHL, WHL, out);
}